// Round 13
// baseline (1975.392 us; speedup 1.0000x reference)
//
#include <hip/hip_runtime.h>

// ---------------- types / helpers ----------------
typedef __attribute__((ext_vector_type(8))) short bf16x8;
typedef __attribute__((ext_vector_type(4))) float f32x4;

#define L_LAYERS 6
#define T_SEQ 1024
#define D_MODEL 1024
#define N_HEAD 16
#define HS 64
#define FF_DIM 4096
#define VOCAB 32000
#define BT_ROWS 4096           // B*T
#define ATTN_SCALE 0.03125f    // D**-0.5 (reference scales by D, not HS)

__device__ __forceinline__ ushort f2bf(float f) {
  unsigned u = __builtin_bit_cast(unsigned, f);
  unsigned r = (u + 0x7fffu + ((u >> 16) & 1u)) >> 16;
  return (ushort)r;
}
__device__ __forceinline__ float waveRedSum(float v) {
#pragma unroll
  for (int off = 32; off; off >>= 1) v += __shfl_xor(v, off);
  return v;
}
// async global->LDS, 16B per lane. LDS dest wave-uniform base; HW adds lane*16.
__device__ __forceinline__ void gload16(const void* g, void* l) {
  __builtin_amdgcn_global_load_lds(
      (const __attribute__((address_space(1))) unsigned int*)g,
      (__attribute__((address_space(3))) unsigned int*)l, 16, 0, 0);
}

// ---------------- embedding ----------------
__global__ __launch_bounds__(256) void embed_kernel(const int* __restrict__ idx,
                                                    const float* __restrict__ tok,
                                                    const float* __restrict__ pos,
                                                    float* __restrict__ x) {
  int row = blockIdx.x;
  int tid = threadIdx.x;
  int t = row & (T_SEQ - 1);
  int id = idx[row];
  float4 tv = ((const float4*)(tok + (size_t)id * D_MODEL))[tid];
  float4 pv = ((const float4*)(pos + (size_t)t * D_MODEL))[tid];
  tv.x += pv.x; tv.y += pv.y; tv.z += pv.z; tv.w += pv.w;
  ((float4*)(x + (size_t)row * D_MODEL))[tid] = tv;
}

// ---------------- LayerNorm f32 -> bf16 (wave-per-row, no barriers) ----------------
__global__ __launch_bounds__(256) void ln_kernel(const float* __restrict__ x,
                                                 const float* __restrict__ g,
                                                 const float* __restrict__ b,
                                                 ushort* __restrict__ out) {
  int tid = threadIdx.x;
  int lane = tid & 63, w = tid >> 6;
  int row = blockIdx.x * 4 + w;
  const float4* xr = (const float4*)(x + (size_t)row * D_MODEL);
  float4 xv[4];
#pragma unroll
  for (int i = 0; i < 4; i++) xv[i] = xr[lane + i * 64];
  float s = 0.0f;
#pragma unroll
  for (int i = 0; i < 4; i++) s += xv[i].x + xv[i].y + xv[i].z + xv[i].w;
  s = waveRedSum(s);
  float mean = s * (1.0f / D_MODEL);
  float v = 0.0f;
#pragma unroll
  for (int i = 0; i < 4; i++) {
    float d0 = xv[i].x - mean, d1 = xv[i].y - mean;
    float d2 = xv[i].z - mean, d3 = xv[i].w - mean;
    v += d0 * d0 + d1 * d1 + d2 * d2 + d3 * d3;
  }
  v = waveRedSum(v);
  float rstd = rsqrtf(v * (1.0f / D_MODEL) + 1e-5f);
  const float4* gr = (const float4*)g;
  const float4* br = (const float4*)b;
  ushort4* orow = (ushort4*)(out + (size_t)row * D_MODEL);
#pragma unroll
  for (int i = 0; i < 4; i++) {
    float4 gv = gr[lane + i * 64], bv = br[lane + i * 64];
    ushort4 o;
    o.x = f2bf((xv[i].x - mean) * rstd * gv.x + bv.x);
    o.y = f2bf((xv[i].y - mean) * rstd * gv.y + bv.y);
    o.z = f2bf((xv[i].z - mean) * rstd * gv.z + bv.z);
    o.w = f2bf((xv[i].w - mean) * rstd * gv.w + bv.w);
    orow[lane + i * 64] = o;
  }
}

// ---------------- weight convert+transpose: W f32 [Kd][Nd] -> WT bf16 [n][Kd] ----------------
__device__ __forceinline__ void wconv_body(const float* __restrict__ W,
                                           ushort* __restrict__ WT,
                                           int Kd, int Nd, int n0, int k0) {
  __shared__ ushort tile[64][72];
  int tid = threadIdx.x;
#pragma unroll
  for (int i = 0; i < 4; i++) {
    int c = tid + i * 256;
    int row = c >> 4, cc = c & 15;
    float4 wv = *(const float4*)&W[(size_t)(k0 + row) * Nd + n0 + cc * 4];
    tile[row][cc * 4 + 0] = f2bf(wv.x);
    tile[row][cc * 4 + 1] = f2bf(wv.y);
    tile[row][cc * 4 + 2] = f2bf(wv.z);
    tile[row][cc * 4 + 3] = f2bf(wv.w);
  }
  __syncthreads();
#pragma unroll
  for (int i = 0; i < 2; i++) {
    int c = tid + i * 256;
    int n = c >> 3, kc = c & 7;
    __align__(16) ushort tmp[8];
#pragma unroll
    for (int j = 0; j < 8; j++) tmp[j] = tile[kc * 8 + j][n];
    *(int4*)&WT[(size_t)(n0 + n) * Kd + k0 + kc * 8] = *(const int4*)tmp;
  }
}

__global__ __launch_bounds__(256) void wconv_kernel(const float* __restrict__ W,
                                                    ushort* __restrict__ WT,
                                                    int Kd, int Nd) {
  wconv_body(W, WT, Kd, Nd, blockIdx.x * 64, blockIdx.y * 64);
}

// one launch per layer: z<4 -> qkv/proj (16x16 tiles each), z in [4,8) -> ff1,
// z in [8,12) -> ff2. grid (16,16,12).
__global__ __launch_bounds__(256) void wconv_layer_kernel(
    const float* __restrict__ Wq, const float* __restrict__ Wk,
    const float* __restrict__ Wv, const float* __restrict__ Wp,
    const float* __restrict__ Wf1, const float* __restrict__ Wf2,
    ushort* __restrict__ wqkvT, ushort* __restrict__ wff1T,
    ushort* __restrict__ wff2T) {
  int z = blockIdx.z;
  int bx = blockIdx.x, by = blockIdx.y;
  if (z < 4) {
    const float* W = (z == 0) ? Wq : (z == 1) ? Wk : (z == 2) ? Wv : Wp;
    wconv_body(W, wqkvT + (size_t)z * D_MODEL * D_MODEL, D_MODEL, D_MODEL,
               bx * 64, by * 64);
  } else if (z < 8) {
    wconv_body(Wf1, wff1T, D_MODEL, FF_DIM, ((z - 4) * 16 + bx) * 64, by * 64);
  } else {
    wconv_body(Wf2, wff2T, FF_DIM, D_MODEL, bx * 64, ((z - 8) * 16 + by) * 64);
  }
}

// ---------------- 2-phase pipelined GEMM (128x128) for proj/FF2 ----------------
template <int BM, int BN, int WM, int WN, int EPI>
__global__ __launch_bounds__(WM * WN * 64, 2) void gemmp_kernel(
    const ushort* __restrict__ A, const ushort* __restrict__ BT, int K,
    const float* __restrict__ bias, float* __restrict__ outf,
    ushort* __restrict__ outb, ushort* __restrict__ outk,
    ushort* __restrict__ outv, int ldo) {
  constexpr int PM = BM / WM, PN = BN / WN;
  constexpr int MR = PM / 16, NR = PN / 16;
  constexpr int ROWS = BM + BN;
  constexpr int NWAVES = WM * WN;
  constexpr int LPW = (ROWS / 8) / NWAVES;
  __shared__ __align__(16) ushort buf[2][ROWS * 64];
  int tid = threadIdx.x;
  int lane = tid & 63, wave = tid >> 6;
  int wm = wave / WN, wn = wave % WN;
  int a = lane & 15, gg = lane >> 4;
  int srow8 = lane >> 3;
  int scol8 = ((lane & 7) ^ (lane >> 3)) * 8;
  int m0 = blockIdx.y * BM, n0 = blockIdx.x * BN;
  f32x4 acc[MR][NR] = {};
  int nt = K >> 6;

  auto STAGE = [&](int t, int d) {
    int k0 = t * 64;
#pragma unroll
    for (int j = 0; j < LPW; j++) {
      int r0 = (wave * LPW + j) * 8;
      if (r0 < BM) {
        gload16(&A[(size_t)(m0 + r0 + srow8) * K + k0 + scol8], &buf[d][r0 * 64]);
      } else {
        gload16(&BT[(size_t)(n0 + (r0 - BM) + srow8) * K + k0 + scol8], &buf[d][r0 * 64]);
      }
    }
  };

  auto COMPUTE = [&](int d) {
    const ushort* bA = &buf[d][0];
    const ushort* bB = &buf[d][BM * 64];
#pragma unroll
    for (int s = 0; s < 2; s++) {
      bf16x8 af[MR], bfr[NR];
#pragma unroll
      for (int i = 0; i < MR; i++) {
        int row = wm * PM + i * 16 + a;
        af[i] = *(const bf16x8*)&bA[row * 64 + (((s * 4 + gg) ^ (a & 7)) * 8)];
      }
#pragma unroll
      for (int j = 0; j < NR; j++) {
        int row = wn * PN + j * 16 + a;
        bfr[j] = *(const bf16x8*)&bB[row * 64 + (((s * 4 + gg) ^ (a & 7)) * 8)];
      }
#pragma unroll
      for (int i = 0; i < MR; i++)
#pragma unroll
        for (int j = 0; j < NR; j++)
          acc[i][j] = __builtin_amdgcn_mfma_f32_16x16x32_bf16(af[i], bfr[j], acc[i][j], 0, 0, 0);
    }
  };

  STAGE(0, 0);
  __syncthreads();
  int cur = 0;
  for (int t = 0; t < nt; t++) {
    if (t + 1 < nt) STAGE(t + 1, cur ^ 1);
    COMPUTE(cur);
    __syncthreads();
    cur ^= 1;
  }

#pragma unroll
  for (int i = 0; i < MR; i++) {
#pragma unroll
    for (int j = 0; j < NR; j++) {
#pragma unroll
      for (int r = 0; r < 4; r++) {
        int mrow = m0 + wm * PM + i * 16 + gg * 4 + r;
        int ncol = n0 + wn * PN + j * 16 + a;
        float v = acc[i][j][r];
        if (EPI == 1) {
          outf[(size_t)mrow * ldo + ncol] += v + bias[ncol];
        } else if (EPI == 2) {
          float t2 = v + bias[ncol];
          outb[(size_t)mrow * ldo + ncol] = f2bf(t2 > 0.0f ? t2 : 0.0f);
        } else {
          outf[(size_t)mrow * ldo + ncol] = v + bias[ncol];
        }
      }
    }
  }
}

// ---------------- fine-phase counted-vmcnt GEMM (256x256, 8 waves 2Mx4N) ----------------
// 4 phases/K-tile: {ds_read quadrant | stage one half-tile | bar | lgkmcnt(0) |
// setprio(1) 16 MFMA setprio(0) | bar}; staggered staging; counted vmcnt(4)/tile.
// SWZ (head): ROW-MAJOR chunked XCD swizzle (R5/R10-verified best for this shape).
// EPI 0: qkv scatter (V written DIRECTLY TRANSPOSED into outv=[BH][HS][T]);
// EPI 2: bf16(relu(acc+bias)); EPI 3: f32 acc+bias + fused two-pass loss partials.
template <int EPI, bool SWZ>
__global__ __launch_bounds__(512, 2) void gemm8_kernel(
    const ushort* __restrict__ A, const ushort* __restrict__ BT, int K,
    const float* __restrict__ bias, float* __restrict__ outf,
    ushort* __restrict__ outb, ushort* __restrict__ outk,
    ushort* __restrict__ outv, int ldo, float2* __restrict__ part) {
  extern __shared__ __align__(16) ushort lds[];   // A[2][256][64] @0, B[2][256][64] @32768
  int tid = threadIdx.x;
  int lane = tid & 63, wave = tid >> 6;    // 8 waves
  int wm = wave >> 2, wn = wave & 3;       // 2M x 4N -> wave tile 128x64
  int a = lane & 15, gg = lane >> 4;
  int bx = blockIdx.x, by = blockIdx.y;
  if (SWZ) {
    int gx = gridDim.x, gy = gridDim.y;
    int nwg = gx * gy;                      // nwg % 8 == 0 required
    int wg = by * gx + bx;
    int id = (wg & 7) * (nwg >> 3) + (wg >> 3);
    bx = id % gx; by = id / gx;             // row-major within XCD chunk
  }
  int m0 = by * 256, n0 = bx * 256;
  int srow = lane >> 3;
  int scol = ((lane & 7) ^ (lane >> 3)) * 8;
  int nt = K >> 6;
  f32x4 acc[8][4] = {};

  auto stageHalf = [&](int t, int which) {
    int d = t & 1;
    int k0 = t * 64;
    const ushort* src = (which < 2) ? A : BT;
    int base0 = ((which < 2) ? m0 : n0) + (which & 1) * 128;
    ushort* dst = lds + ((which < 2) ? 0 : 32768) + d * 16384 + (which & 1) * 8192;
#pragma unroll
    for (int q = 0; q < 2; q++) {
      int r0 = q * 64 + wave * 8;
      gload16(&src[(size_t)(base0 + r0 + srow) * K + k0 + scol], dst + r0 * 64);
    }
  };

  stageHalf(0, 0); stageHalf(0, 1); stageHalf(0, 2); stageHalf(0, 3);
  if (nt > 1) {
    stageHalf(1, 2); stageHalf(1, 3);
    asm volatile("s_waitcnt vmcnt(4)" ::: "memory");
  } else {
    asm volatile("s_waitcnt vmcnt(0)" ::: "memory");
  }
  __builtin_amdgcn_sched_barrier(0);
  __builtin_amdgcn_s_barrier();

  for (int t = 0; t < nt; t++) {
    int d = t & 1;
    const ushort* bA = lds + d * 16384;
    const ushort* bB = lds + 32768 + d * 16384;
    bf16x8 alo[4][2], ahi[4][2], bj01[2][2], bj23[2][2];
    // ---- P0 ----
#pragma unroll
    for (int i = 0; i < 4; i++)
#pragma unroll
      for (int s = 0; s < 2; s++) {
        int row = wm * 128 + i * 16 + a;
        alo[i][s] = *(const bf16x8*)&bA[row * 64 + (((s * 4 + gg) ^ (a & 7)) * 8)];
      }
#pragma unroll
    for (int j = 0; j < 2; j++)
#pragma unroll
      for (int s = 0; s < 2; s++) {
        int row = wn * 64 + j * 16 + a;
        bj01[j][s] = *(const bf16x8*)&bB[row * 64 + (((s * 4 + gg) ^ (a & 7)) * 8)];
      }
    if (t + 1 < nt) stageHalf(t + 1, 0);
    __builtin_amdgcn_s_barrier();
    asm volatile("s_waitcnt lgkmcnt(0)" ::: "memory");
    __builtin_amdgcn_sched_barrier(0);
    __builtin_amdgcn_s_setprio(1);
#pragma unroll
    for (int i = 0; i < 4; i++)
#pragma unroll
      for (int j = 0; j < 2; j++)
#pragma unroll
        for (int s = 0; s < 2; s++)
          acc[i][j] = __builtin_amdgcn_mfma_f32_16x16x32_bf16(alo[i][s], bj01[j][s], acc[i][j], 0, 0, 0);
    __builtin_amdgcn_s_setprio(0);
    __builtin_amdgcn_s_barrier();
    // ---- P1 ----
#pragma unroll
    for (int j = 0; j < 2; j++)
#pragma unroll
      for (int s = 0; s < 2; s++) {
        int row = wn * 64 + (j + 2) * 16 + a;
        bj23[j][s] = *(const bf16x8*)&bB[row * 64 + (((s * 4 + gg) ^ (a & 7)) * 8)];
      }
    if (t + 1 < nt) stageHalf(t + 1, 1);
    __builtin_amdgcn_s_barrier();
    asm volatile("s_waitcnt lgkmcnt(0)" ::: "memory");
    __builtin_amdgcn_sched_barrier(0);
    __builtin_amdgcn_s_setprio(1);
#pragma unroll
    for (int i = 0; i < 4; i++)
#pragma unroll
      for (int j = 0; j < 2; j++)
#pragma unroll
        for (int s = 0; s < 2; s++)
          acc[i][j + 2] = __builtin_amdgcn_mfma_f32_16x16x32_bf16(alo[i][s], bj23[j][s], acc[i][j + 2], 0, 0, 0);
    __builtin_amdgcn_s_setprio(0);
    __builtin_amdgcn_s_barrier();
    // ---- P2 ----
#pragma unroll
    for (int i = 0; i < 4; i++)
#pragma unroll
      for (int s = 0; s < 2; s++) {
        int row = wm * 128 + (i + 4) * 16 + a;
        ahi[i][s] = *(const bf16x8*)&bA[row * 64 + (((s * 4 + gg) ^ (a & 7)) * 8)];
      }
    if (t + 2 < nt) stageHalf(t + 2, 2);
    __builtin_amdgcn_s_barrier();
    asm volatile("s_waitcnt lgkmcnt(0)" ::: "memory");
    __builtin_amdgcn_sched_barrier(0);
    __builtin_amdgcn_s_setprio(1);
#pragma unroll
    for (int i = 0; i < 4; i++)
#pragma unroll
      for (int j = 0; j < 2; j++)
#pragma unroll
        for (int s = 0; s < 2; s++)
          acc[i + 4][j] = __builtin_amdgcn_mfma_f32_16x16x32_bf16(ahi[i][s], bj01[j][s], acc[i + 4][j], 0, 0, 0);
    __builtin_amdgcn_s_setprio(0);
    __builtin_amdgcn_s_barrier();
    // ---- P3 ----
    if (t + 2 < nt) stageHalf(t + 2, 3);
    __builtin_amdgcn_s_barrier();
    __builtin_amdgcn_s_setprio(1);
#pragma unroll
    for (int i = 0; i < 4; i++)
#pragma unroll
      for (int j = 0; j < 2; j++)
#pragma unroll
        for (int s = 0; s < 2; s++)
          acc[i + 4][j + 2] = __builtin_amdgcn_mfma_f32_16x16x32_bf16(ahi[i][s], bj23[j][s], acc[i + 4][j + 2], 0, 0, 0);
    __builtin_amdgcn_s_setprio(0);
    __builtin_amdgcn_sched_barrier(0);
    if (t + 1 < nt) {
      if (t + 2 < nt) asm volatile("s_waitcnt vmcnt(4)" ::: "memory");
      else            asm volatile("s_waitcnt vmcnt(0)" ::: "memory");
      __builtin_amdgcn_sched_barrier(0);
    }
    __builtin_amdgcn_s_barrier();
  }

  if (EPI == 3) {
    // fold bias, store logits f32
    float bj[4];
#pragma unroll
    for (int j = 0; j < 4; j++) bj[j] = bias[n0 + wn * 64 + j * 16 + a];
#pragma unroll
    for (int i = 0; i < 8; i++)
#pragma unroll
      for (int j = 0; j < 4; j++)
#pragma unroll
        for (int r = 0; r < 4; r++) acc[i][j][r] += bj[j];
#pragma unroll
    for (int i = 0; i < 8; i++)
#pragma unroll
      for (int j = 0; j < 4; j++)
#pragma unroll
        for (int r = 0; r < 4; r++) {
          int mrow = m0 + wm * 128 + i * 16 + gg * 4 + r;
          int ncol = n0 + wn * 64 + j * 16 + a;
          outf[(size_t)mrow * ldo + ncol] = acc[i][j][r];
        }
    // two-pass per-row stats over this wave's 64-col strip (exact max, then sumexp)
    float2* sm = (float2*)lds;   // [256 rows][4 wn]
#pragma unroll
    for (int i = 0; i < 8; i++) {
#pragma unroll
      for (int r = 0; r < 4; r++) {
        float pm = fmaxf(fmaxf(acc[i][0][r], acc[i][1][r]),
                         fmaxf(acc[i][2][r], acc[i][3][r]));
#pragma unroll
        for (int off = 1; off < 16; off <<= 1) pm = fmaxf(pm, __shfl_xor(pm, off));
        float ps = __expf(acc[i][0][r] - pm) + __expf(acc[i][1][r] - pm) +
                   __expf(acc[i][2][r] - pm) + __expf(acc[i][3][r] - pm);
#pragma unroll
        for (int off = 1; off < 16; off <<= 1) ps += __shfl_xor(ps, off);
        if (a == 0) {
          float2 v2; v2.x = pm; v2.y = ps;
          sm[(wm * 128 + i * 16 + gg * 4 + r) * 4 + wn] = v2;
        }
      }
    }
    __syncthreads();
    if (tid < 256) {
      float2 p0 = sm[tid * 4 + 0], p1 = sm[tid * 4 + 1];
      float2 p2 = sm[tid * 4 + 2], p3 = sm[tid * 4 + 3];
      float M = fmaxf(fmaxf(p0.x, p1.x), fmaxf(p2.x, p3.x));
      float S = p0.y * __expf(p0.x - M) + p1.y * __expf(p1.x - M) +
                p2.y * __expf(p2.x - M) + p3.y * __expf(p3.x - M);
      float2 o2; o2.x = M; o2.y = S;
      part[(size_t)(m0 + tid) * 128 + (n0 >> 8)] = o2;
    }
    return;
  }

#pragma unroll
  for (int i = 0; i < 8; i++) {
#pragma unroll
    for (int j = 0; j < 4; j++) {
#pragma unroll
      for (int r = 0; r < 4; r++) {
        int mrow = m0 + wm * 128 + i * 16 + gg * 4 + r;
        int ncol = n0 + wn * 64 + j * 16 + a;
        float v = acc[i][j][r];
        if (EPI == 0) {
          int which = ncol >> 10;
          int n1 = ncol & 1023;
          int h = n1 >> 6, sidx = n1 & 63;
          int bb = mrow >> 10, tt = mrow & 1023;
          if (which == 2) {
            // V written directly transposed: [BH][HS][T]
            outv[(((size_t)(bb * N_HEAD + h)) * HS + sidx) * T_SEQ + tt] = f2bf(v);
          } else {
            ushort* dst = (which == 0) ? outb : outk;
            dst[(((size_t)(bb * N_HEAD + h)) * T_SEQ + tt) * HS + sidx] = f2bf(v);
          }
        } else if (EPI == 2) {
          float t2 = v + bias[ncol];
          outb[(size_t)mrow * ldo + ncol] = f2bf(t2 > 0.0f ? t2 : 0.0f);
        }
      }
    }
  }
}

// ---------------- fused causal flash attention (LDS-staged K/V, R10-verified) ----------------
__global__ __launch_bounds__(256) void attn_kernel(const ushort* __restrict__ q,
                                                   const ushort* __restrict__ k,
                                                   const ushort* __restrict__ vT,
                                                   ushort* __restrict__ o) {
  __shared__ __align__(16) ushort Ksm[64 * 72];
  __shared__ __align__(16) ushort Vsm[64 * 72];
  __shared__ __align__(16) ushort Psm[4][16 * 72];
  int tid = threadIdx.x;
  int lane = tid & 63, w = tid >> 6;
  int a = lane & 15, gg = lane >> 4;
  int qt = blockIdx.x, bh = blockIdx.y;
  int qrow_b = qt * 64 + w * 16;
  int qmy = qrow_b + a;

  bf16x8 qf[2];
  const ushort* qbase = q + ((size_t)bh * T_SEQ + qmy) * HS;
  qf[0] = *(const bf16x8*)&qbase[gg * 8];
  qf[1] = *(const bf16x8*)&qbase[32 + gg * 8];

  float m_run = -__builtin_inff();
  float l_run = 0.0f;
  f32x4 oacc[4] = {};
  int nkt = qt + 1;

  for (int kt = 0; kt < nkt; kt++) {
    int k0 = kt * 64;
    __syncthreads();
#pragma unroll
    for (int i = 0; i < 2; i++) {
      int c = tid + i * 256;
      int row = c >> 3, cc = c & 7;
      *(int4*)&Ksm[row * 72 + cc * 8] =
          *(const int4*)&k[((size_t)bh * T_SEQ + k0 + row) * HS + cc * 8];
      *(int4*)&Vsm[row * 72 + cc * 8] =
          *(const int4*)&vT[((size_t)bh * HS + row) * T_SEQ + k0 + cc * 8];
    }
    __syncthreads();

    f32x4 st[4] = {};
#pragma unroll
    for (int ku = 0; ku < 4; ku++) {
#pragma unroll
      for (int s = 0; s < 2; s++) {
        bf16x8 kf = *(const bf16x8*)&Ksm[(ku * 16 + a) * 72 + s * 32 + gg * 8];
        st[ku] = __builtin_amdgcn_mfma_f32_16x16x32_bf16(kf, qf[s], st[ku], 0, 0, 0);
      }
    }

    float pv[16];
    float pm = -__builtin_inff();
#pragma unroll
    for (int ku = 0; ku < 4; ku++) {
#pragma unroll
      for (int r = 0; r < 4; r++) {
        int u = k0 + ku * 16 + gg * 4 + r;
        float val = (u <= qmy) ? st[ku][r] * ATTN_SCALE : -__builtin_inff();
        pv[ku * 4 + r] = val;
        pm = fmaxf(pm, val);
      }
    }
    pm = fmaxf(pm, __shfl_xor(pm, 16));
    pm = fmaxf(pm, __shfl_xor(pm, 32));
    float m_new = fmaxf(m_run, pm);
    float cfac = __expf(m_run - m_new);   // m_run=-inf first tile -> 0
    float tsum = 0.0f;
#pragma unroll
    for (int xi = 0; xi < 16; xi++) {
      float p = __expf(pv[xi] - m_new);
      pv[xi] = p;
      tsum += p;
    }
    tsum += __shfl_xor(tsum, 16);
    tsum += __shfl_xor(tsum, 32);
    l_run = l_run * cfac + tsum;
    m_run = m_new;

    ushort* P = (ushort*)&Psm[w][0];
    asm volatile("s_waitcnt lgkmcnt(0)" ::: "memory");
#pragma unroll
    for (int ku = 0; ku < 4; ku++) {
      ushort4 pw;
      pw.x = f2bf(pv[ku * 4 + 0]);
      pw.y = f2bf(pv[ku * 4 + 1]);
      pw.z = f2bf(pv[ku * 4 + 2]);
      pw.w = f2bf(pv[ku * 4 + 3]);
      *(ushort4*)&P[a * 72 + ku * 16 + gg * 4] = pw;
    }
#pragma unroll
    for (int r = 0; r < 4; r++) {
      float cr = __shfl(cfac, gg * 4 + r);
#pragma unroll
      for (int nb = 0; nb < 4; nb++) oacc[nb][r] *= cr;
    }
    asm volatile("s_waitcnt lgkmcnt(0)" ::: "memory");
#pragma unroll
    for (int kb = 0; kb < 2; kb++) {
      bf16x8 pa = *(const bf16x8*)&P[a * 72 + kb * 32 + gg * 8];
#pragma unroll
      for (int nb = 0; nb < 4; nb++) {
        bf16x8 vb = *(const bf16x8*)&Vsm[(nb * 16 + a) * 72 + kb * 32 + gg * 8];
        oacc[nb] = __builtin_amdgcn_mfma_f32_16x16x32_bf16(pa, vb, oacc[nb], 0, 0, 0);
      }
    }
  }

  float linv = 1.0f / l_run;
  int bb = bh >> 4, hh = bh & 15;
#pragma unroll
  for (int r = 0; r < 4; r++) {
    float li = __shfl(linv, gg * 4 + r);
    int qr = qrow_b + gg * 4 + r;
#pragma unroll
    for (int nb = 0; nb < 4; nb++) {
      o[((size_t)(bb * T_SEQ + qr)) * D_MODEL + hh * HS + nb * 16 + a] =
          f2bf(oacc[nb][r] * li);
    }
  }
}

// ---------------- loss: reduce per-block partials (125 per row) ----------------
__global__ __launch_bounds__(64) void loss_rows_kernel(const float2* __restrict__ part,
                                                       const float* __restrict__ logits,
                                                       const int* __restrict__ tgt,
                                                       float* __restrict__ row_loss) {
  int row = blockIdx.x;
  int l = threadIdx.x;
  float m = -__builtin_inff(), s = 0.0f;
#pragma unroll
  for (int q = 0; q < 2; q++) {
    int c = l * 2 + q;
    if (c < 125) {
      float2 p = part[(size_t)row * 128 + c];
      float nm = fmaxf(m, p.x);
      s = s * __expf(m - nm) + p.y * __expf(p.x - nm);
      m = nm;
    }
  }
#pragma unroll
  for (int off = 1; off < 64; off <<= 1) {
    float om = __shfl_xor(m, off), os = __shfl_xor(s, off);
    float nm = fmaxf(m, om);
    s = s * __expf(m - nm) + os * __expf(om - nm);
    m = nm;
  }
  if (l == 0)
    row_loss[row] = m + logf(s) - logits[(size_t)row * VOCAB + tgt[row]];
}

__global__ __launch_bounds__(256) void loss_final_kernel(const float* __restrict__ row_loss,
                                                         float* __restrict__ out) {
  int tid = threadIdx.x;
  __shared__ float red[4];
  float s = 0.0f;
  for (int i = tid; i < BT_ROWS; i += 256) s += row_loss[i];
  s = waveRedSum(s);
  if ((tid & 63) == 0) red[tid >> 6] = s;
  __syncthreads();
  if (tid == 0) out[0] = (red[0] + red[1] + red[2] + red[3]) * (1.0f / BT_ROWS);
}

// ---------------- orchestration ----------------
extern "C" void kernel_launch(void* const* d_in, const int* in_sizes, int n_in,
                              void* d_out, int out_size, void* d_ws, size_t ws_size,
                              hipStream_t stream) {
  const int* idx = (const int*)d_in[0];
  const int* tgt = (const int*)d_in[1];
  const float* tok_emb = (const float*)d_in[2];
  const float* pos_emb = (const float*)d_in[3];
  const float* Wq = (const float*)d_in[4];
  const float* Wk = (const float*)d_in[5];
  const float* Wv = (const float*)d_in[6];
  const float* proj_w = (const float*)d_in[7];
  const float* proj_b = (const float*)d_in[8];
  const float* ln1_g = (const float*)d_in[9];
  const float* ln1_b = (const float*)d_in[10];
  const float* ln2_g = (const float*)d_in[11];
  const float* ln2_b = (const float*)d_in[12];
  const float* ff_w1 = (const float*)d_in[13];
  const float* ff_b1 = (const float*)d_in[14];
  const float* ff_w2 = (const float*)d_in[15];
  const float* ff_b2 = (const float*)d_in[16];
  const float* lnf_g = (const float*)d_in[17];
  const float* lnf_b = (const float*)d_in[18];
  const float* head_w = (const float*)d_in[19];
  const float* head_b = (const float*)d_in[20];

  char* ws = (char*)d_ws;
  size_t off = 0;
  float* x = (float*)(ws + off); off += (size_t)BT_ROWS * D_MODEL * 4;
  ushort* h = (ushort*)(ws + off); off += (size_t)BT_ROWS * D_MODEL * 2;
  ushort* qb = (ushort*)(ws + off); off += (size_t)BT_ROWS * D_MODEL * 2;
  ushort* kb = (ushort*)(ws + off); off += (size_t)BT_ROWS * D_MODEL * 2;
  ushort* vb = (ushort*)(ws + off); off += (size_t)BT_ROWS * D_MODEL * 2;   // unused (kept for layout stability)
  ushort* vTb = (ushort*)(ws + off); off += (size_t)BT_ROWS * D_MODEL * 2;
  ushort* ob = (ushort*)(ws + off); off += (size_t)BT_ROWS * D_MODEL * 2;
  ushort* ffb = (ushort*)(ws + off); off += (size_t)BT_ROWS * FF_DIM * 2;
  ushort* wqkvT = (ushort*)(ws + off); off += (size_t)4 * D_MODEL * D_MODEL * 2;
  ushort* wprojT = wqkvT + (size_t)3 * D_MODEL * D_MODEL;
  ushort* wff1T = (ushort*)(ws + off); off += (size_t)FF_DIM * D_MODEL * 2;
  ushort* wff2T = (ushort*)(ws + off); off += (size_t)D_MODEL * FF_DIM * 2;
  float* row_loss = (float*)(ws + off); off += (size_t)BT_ROWS * 4;
  float2* part = (float2*)(ws + off); off += (size_t)BT_ROWS * 128 * 8;   // 4 MB
  // head weights (32000x1024 bf16 = 65.5 MB) reuse the dead qb..ffb region (75.5 MB)
  ushort* headT = qb;
  (void)vb;

  float* logits = (float*)d_out;

  embed_kernel<<<BT_ROWS, 256, 0, stream>>>(idx, tok_emb, pos_emb, x);

  for (int l = 0; l < L_LAYERS; l++) {
    size_t wo = (size_t)l * D_MODEL * D_MODEL;
    size_t fo = (size_t)l * D_MODEL * FF_DIM;
    // all per-layer weight conversions in ONE launch
    wconv_layer_kernel<<<dim3(16, 16, 12), 256, 0, stream>>>(
        Wq + wo, Wk + wo, Wv + wo, proj_w + wo, ff_w1 + fo, ff_w2 + fo,
        wqkvT, wff1T, wff2T);

    ln_kernel<<<BT_ROWS / 4, 256, 0, stream>>>(x, ln1_g + l * D_MODEL, ln1_b + l * D_MODEL, h);
    // QKV gemm (N=3072): 256x256 fine-phase, grid 12x16; V written pre-transposed
    gemm8_kernel<0, false><<<dim3(12, 16), 512, 131072, stream>>>(
        h, wqkvT, D_MODEL, nullptr, nullptr, qb, kb, vTb, 0, nullptr);
    attn_kernel<<<dim3(16, 64), 256, 0, stream>>>(qb, kb, vTb, ob);
    // proj + residual: 128x128 2-phase, grid 8x32
    gemmp_kernel<128, 128, 2, 2, 1><<<dim3(8, 32), 256, 0, stream>>>(
        ob, wprojT, D_MODEL, proj_b + l * D_MODEL, x, nullptr, nullptr, nullptr, D_MODEL);
    ln_kernel<<<BT_ROWS / 4, 256, 0, stream>>>(x, ln2_g + l * D_MODEL, ln2_b + l * D_MODEL, h);
    // FF1: 256x256 fine-phase, grid 16x16
    gemm8_kernel<2, false><<<dim3(16, 16), 512, 131072, stream>>>(
        h, wff1T, D_MODEL, ff_b1 + (size_t)l * FF_DIM, nullptr, ffb, nullptr, nullptr,
        FF_DIM, nullptr);
    // FF2 + residual: 128x128 2-phase, grid 8x32, K=4096
    gemmp_kernel<128, 128, 2, 2, 1><<<dim3(8, 32), 256, 0, stream>>>(
        ffb, wff2T, FF_DIM, ff_b2 + l * D_MODEL, x, nullptr, nullptr, nullptr, D_MODEL);
  }

  ln_kernel<<<BT_ROWS / 4, 256, 0, stream>>>(x, lnf_g, lnf_b, h);

  // head: one GEMM N=32000, fine-phase + ROW-MAJOR XCD swizzle + fused loss partials
  wconv_kernel<<<dim3(500, 16), 256, 0, stream>>>(head_w, headT, D_MODEL, VOCAB);
  gemm8_kernel<3, true><<<dim3(125, 16), 512, 131072, stream>>>(
      h, headT, D_MODEL, head_b, logits, nullptr, nullptr, nullptr, VOCAB, part);

  loss_rows_kernel<<<BT_ROWS, 64, 0, stream>>>(part, logits, tgt, row_loss);
  loss_final_kernel<<<1, 256, 0, stream>>>(row_loss, logits + (size_t)BT_ROWS * VOCAB);
}

// Round 14
// 1864.363 us; speedup vs baseline: 1.0596x; 1.0596x over previous
//
#include <hip/hip_runtime.h>

// ---------------- types / helpers ----------------
typedef __attribute__((ext_vector_type(8))) short bf16x8;
typedef __attribute__((ext_vector_type(4))) float f32x4;

#define L_LAYERS 6
#define T_SEQ 1024
#define D_MODEL 1024
#define N_HEAD 16
#define HS 64
#define FF_DIM 4096
#define VOCAB 32000
#define BT_ROWS 4096           // B*T
#define ATTN_SCALE 0.03125f    // D**-0.5 (reference scales by D, not HS)

__device__ __forceinline__ ushort f2bf(float f) {
  unsigned u = __builtin_bit_cast(unsigned, f);
  unsigned r = (u + 0x7fffu + ((u >> 16) & 1u)) >> 16;
  return (ushort)r;
}
__device__ __forceinline__ float waveRedSum(float v) {
#pragma unroll
  for (int off = 32; off; off >>= 1) v += __shfl_xor(v, off);
  return v;
}
// async global->LDS, 16B per lane. LDS dest wave-uniform base; HW adds lane*16.
__device__ __forceinline__ void gload16(const void* g, void* l) {
  __builtin_amdgcn_global_load_lds(
      (const __attribute__((address_space(1))) unsigned int*)g,
      (__attribute__((address_space(3))) unsigned int*)l, 16, 0, 0);
}

// ---------------- embedding ----------------
__global__ __launch_bounds__(256) void embed_kernel(const int* __restrict__ idx,
                                                    const float* __restrict__ tok,
                                                    const float* __restrict__ pos,
                                                    float* __restrict__ x) {
  int row = blockIdx.x;
  int tid = threadIdx.x;
  int t = row & (T_SEQ - 1);
  int id = idx[row];
  float4 tv = ((const float4*)(tok + (size_t)id * D_MODEL))[tid];
  float4 pv = ((const float4*)(pos + (size_t)t * D_MODEL))[tid];
  tv.x += pv.x; tv.y += pv.y; tv.z += pv.z; tv.w += pv.w;
  ((float4*)(x + (size_t)row * D_MODEL))[tid] = tv;
}

// ---------------- LayerNorm f32 -> bf16 (wave-per-row, no barriers) ----------------
__global__ __launch_bounds__(256) void ln_kernel(const float* __restrict__ x,
                                                 const float* __restrict__ g,
                                                 const float* __restrict__ b,
                                                 ushort* __restrict__ out) {
  int tid = threadIdx.x;
  int lane = tid & 63, w = tid >> 6;
  int row = blockIdx.x * 4 + w;
  const float4* xr = (const float4*)(x + (size_t)row * D_MODEL);
  float4 xv[4];
#pragma unroll
  for (int i = 0; i < 4; i++) xv[i] = xr[lane + i * 64];
  float s = 0.0f;
#pragma unroll
  for (int i = 0; i < 4; i++) s += xv[i].x + xv[i].y + xv[i].z + xv[i].w;
  s = waveRedSum(s);
  float mean = s * (1.0f / D_MODEL);
  float v = 0.0f;
#pragma unroll
  for (int i = 0; i < 4; i++) {
    float d0 = xv[i].x - mean, d1 = xv[i].y - mean;
    float d2 = xv[i].z - mean, d3 = xv[i].w - mean;
    v += d0 * d0 + d1 * d1 + d2 * d2 + d3 * d3;
  }
  v = waveRedSum(v);
  float rstd = rsqrtf(v * (1.0f / D_MODEL) + 1e-5f);
  const float4* gr = (const float4*)g;
  const float4* br = (const float4*)b;
  ushort4* orow = (ushort4*)(out + (size_t)row * D_MODEL);
#pragma unroll
  for (int i = 0; i < 4; i++) {
    float4 gv = gr[lane + i * 64], bv = br[lane + i * 64];
    ushort4 o;
    o.x = f2bf((xv[i].x - mean) * rstd * gv.x + bv.x);
    o.y = f2bf((xv[i].y - mean) * rstd * gv.y + bv.y);
    o.z = f2bf((xv[i].z - mean) * rstd * gv.z + bv.z);
    o.w = f2bf((xv[i].w - mean) * rstd * gv.w + bv.w);
    orow[lane + i * 64] = o;
  }
}

// ---------------- weight convert+transpose: W f32 [Kd][Nd] -> WT bf16 [n][Kd] ----------------
__device__ __forceinline__ void wconv_body(const float* __restrict__ W,
                                           ushort* __restrict__ WT,
                                           int Kd, int Nd, int n0, int k0) {
  __shared__ ushort tile[64][72];
  int tid = threadIdx.x;
#pragma unroll
  for (int i = 0; i < 4; i++) {
    int c = tid + i * 256;
    int row = c >> 4, cc = c & 15;
    float4 wv = *(const float4*)&W[(size_t)(k0 + row) * Nd + n0 + cc * 4];
    tile[row][cc * 4 + 0] = f2bf(wv.x);
    tile[row][cc * 4 + 1] = f2bf(wv.y);
    tile[row][cc * 4 + 2] = f2bf(wv.z);
    tile[row][cc * 4 + 3] = f2bf(wv.w);
  }
  __syncthreads();
#pragma unroll
  for (int i = 0; i < 2; i++) {
    int c = tid + i * 256;
    int n = c >> 3, kc = c & 7;
    __align__(16) ushort tmp[8];
#pragma unroll
    for (int j = 0; j < 8; j++) tmp[j] = tile[kc * 8 + j][n];
    *(int4*)&WT[(size_t)(n0 + n) * Kd + k0 + kc * 8] = *(const int4*)tmp;
  }
}

__global__ __launch_bounds__(256) void wconv_kernel(const float* __restrict__ W,
                                                    ushort* __restrict__ WT,
                                                    int Kd, int Nd) {
  wconv_body(W, WT, Kd, Nd, blockIdx.x * 64, blockIdx.y * 64);
}

// one launch per layer: z<4 -> qkv/proj (16x16 tiles each), z in [4,8) -> ff1,
// z in [8,12) -> ff2. grid (16,16,12).
__global__ __launch_bounds__(256) void wconv_layer_kernel(
    const float* __restrict__ Wq, const float* __restrict__ Wk,
    const float* __restrict__ Wv, const float* __restrict__ Wp,
    const float* __restrict__ Wf1, const float* __restrict__ Wf2,
    ushort* __restrict__ wqkvT, ushort* __restrict__ wff1T,
    ushort* __restrict__ wff2T) {
  int z = blockIdx.z;
  int bx = blockIdx.x, by = blockIdx.y;
  if (z < 4) {
    const float* W = (z == 0) ? Wq : (z == 1) ? Wk : (z == 2) ? Wv : Wp;
    wconv_body(W, wqkvT + (size_t)z * D_MODEL * D_MODEL, D_MODEL, D_MODEL,
               bx * 64, by * 64);
  } else if (z < 8) {
    wconv_body(Wf1, wff1T, D_MODEL, FF_DIM, ((z - 4) * 16 + bx) * 64, by * 64);
  } else {
    wconv_body(Wf2, wff2T, FF_DIM, D_MODEL, bx * 64, ((z - 8) * 16 + by) * 64);
  }
}

// ---------------- bf16 transpose: v [BH][T][HS] -> vT [BH][HS][T] ----------------
__global__ __launch_bounds__(256) void vtrans_kernel(const ushort* __restrict__ v,
                                                     ushort* __restrict__ vT) {
  __shared__ ushort tile[64][72];
  int bh = blockIdx.y;
  int t0 = blockIdx.x * 64;
  int tid = threadIdx.x;
#pragma unroll
  for (int i = 0; i < 2; i++) {
    int c = tid + i * 256;
    int row = c >> 3, cc = c & 7;
    *(int4*)&tile[row][cc * 8] =
        *(const int4*)&v[((size_t)bh * T_SEQ + t0 + row) * HS + cc * 8];
  }
  __syncthreads();
#pragma unroll
  for (int i = 0; i < 2; i++) {
    int c = tid + i * 256;
    int hs = c >> 3, tc = c & 7;
    __align__(16) ushort tmp[8];
#pragma unroll
    for (int j = 0; j < 8; j++) tmp[j] = tile[tc * 8 + j][hs];
    *(int4*)&vT[((size_t)bh * HS + hs) * T_SEQ + t0 + tc * 8] = *(const int4*)tmp;
  }
}

// ---------------- 2-phase pipelined GEMM (128x128) for proj/FF2 ----------------
template <int BM, int BN, int WM, int WN, int EPI>
__global__ __launch_bounds__(WM * WN * 64, 2) void gemmp_kernel(
    const ushort* __restrict__ A, const ushort* __restrict__ BT, int K,
    const float* __restrict__ bias, float* __restrict__ outf,
    ushort* __restrict__ outb, ushort* __restrict__ outk,
    ushort* __restrict__ outv, int ldo) {
  constexpr int PM = BM / WM, PN = BN / WN;
  constexpr int MR = PM / 16, NR = PN / 16;
  constexpr int ROWS = BM + BN;
  constexpr int NWAVES = WM * WN;
  constexpr int LPW = (ROWS / 8) / NWAVES;
  __shared__ __align__(16) ushort buf[2][ROWS * 64];
  int tid = threadIdx.x;
  int lane = tid & 63, wave = tid >> 6;
  int wm = wave / WN, wn = wave % WN;
  int a = lane & 15, gg = lane >> 4;
  int srow8 = lane >> 3;
  int scol8 = ((lane & 7) ^ (lane >> 3)) * 8;
  int m0 = blockIdx.y * BM, n0 = blockIdx.x * BN;
  f32x4 acc[MR][NR] = {};
  int nt = K >> 6;

  auto STAGE = [&](int t, int d) {
    int k0 = t * 64;
#pragma unroll
    for (int j = 0; j < LPW; j++) {
      int r0 = (wave * LPW + j) * 8;
      if (r0 < BM) {
        gload16(&A[(size_t)(m0 + r0 + srow8) * K + k0 + scol8], &buf[d][r0 * 64]);
      } else {
        gload16(&BT[(size_t)(n0 + (r0 - BM) + srow8) * K + k0 + scol8], &buf[d][r0 * 64]);
      }
    }
  };

  auto COMPUTE = [&](int d) {
    const ushort* bA = &buf[d][0];
    const ushort* bB = &buf[d][BM * 64];
#pragma unroll
    for (int s = 0; s < 2; s++) {
      bf16x8 af[MR], bfr[NR];
#pragma unroll
      for (int i = 0; i < MR; i++) {
        int row = wm * PM + i * 16 + a;
        af[i] = *(const bf16x8*)&bA[row * 64 + (((s * 4 + gg) ^ (a & 7)) * 8)];
      }
#pragma unroll
      for (int j = 0; j < NR; j++) {
        int row = wn * PN + j * 16 + a;
        bfr[j] = *(const bf16x8*)&bB[row * 64 + (((s * 4 + gg) ^ (a & 7)) * 8)];
      }
#pragma unroll
      for (int i = 0; i < MR; i++)
#pragma unroll
        for (int j = 0; j < NR; j++)
          acc[i][j] = __builtin_amdgcn_mfma_f32_16x16x32_bf16(af[i], bfr[j], acc[i][j], 0, 0, 0);
    }
  };

  STAGE(0, 0);
  __syncthreads();
  int cur = 0;
  for (int t = 0; t < nt; t++) {
    if (t + 1 < nt) STAGE(t + 1, cur ^ 1);
    COMPUTE(cur);
    __syncthreads();
    cur ^= 1;
  }

#pragma unroll
  for (int i = 0; i < MR; i++) {
#pragma unroll
    for (int j = 0; j < NR; j++) {
#pragma unroll
      for (int r = 0; r < 4; r++) {
        int mrow = m0 + wm * PM + i * 16 + gg * 4 + r;
        int ncol = n0 + wn * PN + j * 16 + a;
        float v = acc[i][j][r];
        if (EPI == 1) {
          outf[(size_t)mrow * ldo + ncol] += v + bias[ncol];
        } else if (EPI == 2) {
          float t2 = v + bias[ncol];
          outb[(size_t)mrow * ldo + ncol] = f2bf(t2 > 0.0f ? t2 : 0.0f);
        } else {
          outf[(size_t)mrow * ldo + ncol] = v + bias[ncol];
        }
      }
    }
  }
}

// ---------------- fine-phase counted-vmcnt GEMM (256x256, 8 waves 2Mx4N) ----------------
// 4 phases/K-tile: {ds_read quadrant | stage one half-tile | bar | lgkmcnt(0) |
// setprio(1) 16 MFMA setprio(0) | bar}; staggered staging; counted vmcnt(4)/tile.
// SWZ (head): ROW-MAJOR chunked XCD swizzle (R5/R10-verified best for this shape).
// EPI 0: qkv scatter; EPI 2: bf16(relu(acc+bias)); EPI 3: f32 acc+bias + fused
// per-row loss partials via TWO-PASS (exact max then sumexp) -> part[row][bx].
template <int EPI, bool SWZ>
__global__ __launch_bounds__(512, 2) void gemm8_kernel(
    const ushort* __restrict__ A, const ushort* __restrict__ BT, int K,
    const float* __restrict__ bias, float* __restrict__ outf,
    ushort* __restrict__ outb, ushort* __restrict__ outk,
    ushort* __restrict__ outv, int ldo, float2* __restrict__ part) {
  extern __shared__ __align__(16) ushort lds[];   // A[2][256][64] @0, B[2][256][64] @32768
  int tid = threadIdx.x;
  int lane = tid & 63, wave = tid >> 6;    // 8 waves
  int wm = wave >> 2, wn = wave & 3;       // 2M x 4N -> wave tile 128x64
  int a = lane & 15, gg = lane >> 4;
  int bx = blockIdx.x, by = blockIdx.y;
  if (SWZ) {
    int gx = gridDim.x, gy = gridDim.y;
    int nwg = gx * gy;                      // nwg % 8 == 0 required
    int wg = by * gx + bx;
    int id = (wg & 7) * (nwg >> 3) + (wg >> 3);
    bx = id % gx; by = id / gx;             // row-major within XCD chunk
  }
  int m0 = by * 256, n0 = bx * 256;
  int srow = lane >> 3;
  int scol = ((lane & 7) ^ (lane >> 3)) * 8;
  int nt = K >> 6;
  f32x4 acc[8][4] = {};

  auto stageHalf = [&](int t, int which) {
    int d = t & 1;
    int k0 = t * 64;
    const ushort* src = (which < 2) ? A : BT;
    int base0 = ((which < 2) ? m0 : n0) + (which & 1) * 128;
    ushort* dst = lds + ((which < 2) ? 0 : 32768) + d * 16384 + (which & 1) * 8192;
#pragma unroll
    for (int q = 0; q < 2; q++) {
      int r0 = q * 64 + wave * 8;
      gload16(&src[(size_t)(base0 + r0 + srow) * K + k0 + scol], dst + r0 * 64);
    }
  };

  stageHalf(0, 0); stageHalf(0, 1); stageHalf(0, 2); stageHalf(0, 3);
  if (nt > 1) {
    stageHalf(1, 2); stageHalf(1, 3);
    asm volatile("s_waitcnt vmcnt(4)" ::: "memory");
  } else {
    asm volatile("s_waitcnt vmcnt(0)" ::: "memory");
  }
  __builtin_amdgcn_sched_barrier(0);
  __builtin_amdgcn_s_barrier();

  for (int t = 0; t < nt; t++) {
    int d = t & 1;
    const ushort* bA = lds + d * 16384;
    const ushort* bB = lds + 32768 + d * 16384;
    bf16x8 alo[4][2], ahi[4][2], bj01[2][2], bj23[2][2];
    // ---- P0 ----
#pragma unroll
    for (int i = 0; i < 4; i++)
#pragma unroll
      for (int s = 0; s < 2; s++) {
        int row = wm * 128 + i * 16 + a;
        alo[i][s] = *(const bf16x8*)&bA[row * 64 + (((s * 4 + gg) ^ (a & 7)) * 8)];
      }
#pragma unroll
    for (int j = 0; j < 2; j++)
#pragma unroll
      for (int s = 0; s < 2; s++) {
        int row = wn * 64 + j * 16 + a;
        bj01[j][s] = *(const bf16x8*)&bB[row * 64 + (((s * 4 + gg) ^ (a & 7)) * 8)];
      }
    if (t + 1 < nt) stageHalf(t + 1, 0);
    __builtin_amdgcn_s_barrier();
    asm volatile("s_waitcnt lgkmcnt(0)" ::: "memory");
    __builtin_amdgcn_sched_barrier(0);
    __builtin_amdgcn_s_setprio(1);
#pragma unroll
    for (int i = 0; i < 4; i++)
#pragma unroll
      for (int j = 0; j < 2; j++)
#pragma unroll
        for (int s = 0; s < 2; s++)
          acc[i][j] = __builtin_amdgcn_mfma_f32_16x16x32_bf16(alo[i][s], bj01[j][s], acc[i][j], 0, 0, 0);
    __builtin_amdgcn_s_setprio(0);
    __builtin_amdgcn_s_barrier();
    // ---- P1 ----
#pragma unroll
    for (int j = 0; j < 2; j++)
#pragma unroll
      for (int s = 0; s < 2; s++) {
        int row = wn * 64 + (j + 2) * 16 + a;
        bj23[j][s] = *(const bf16x8*)&bB[row * 64 + (((s * 4 + gg) ^ (a & 7)) * 8)];
      }
    if (t + 1 < nt) stageHalf(t + 1, 1);
    __builtin_amdgcn_s_barrier();
    asm volatile("s_waitcnt lgkmcnt(0)" ::: "memory");
    __builtin_amdgcn_sched_barrier(0);
    __builtin_amdgcn_s_setprio(1);
#pragma unroll
    for (int i = 0; i < 4; i++)
#pragma unroll
      for (int j = 0; j < 2; j++)
#pragma unroll
        for (int s = 0; s < 2; s++)
          acc[i][j + 2] = __builtin_amdgcn_mfma_f32_16x16x32_bf16(alo[i][s], bj23[j][s], acc[i][j + 2], 0, 0, 0);
    __builtin_amdgcn_s_setprio(0);
    __builtin_amdgcn_s_barrier();
    // ---- P2 ----
#pragma unroll
    for (int i = 0; i < 4; i++)
#pragma unroll
      for (int s = 0; s < 2; s++) {
        int row = wm * 128 + (i + 4) * 16 + a;
        ahi[i][s] = *(const bf16x8*)&bA[row * 64 + (((s * 4 + gg) ^ (a & 7)) * 8)];
      }
    if (t + 2 < nt) stageHalf(t + 2, 2);
    __builtin_amdgcn_s_barrier();
    asm volatile("s_waitcnt lgkmcnt(0)" ::: "memory");
    __builtin_amdgcn_sched_barrier(0);
    __builtin_amdgcn_s_setprio(1);
#pragma unroll
    for (int i = 0; i < 4; i++)
#pragma unroll
      for (int j = 0; j < 2; j++)
#pragma unroll
        for (int s = 0; s < 2; s++)
          acc[i + 4][j] = __builtin_amdgcn_mfma_f32_16x16x32_bf16(ahi[i][s], bj01[j][s], acc[i + 4][j], 0, 0, 0);
    __builtin_amdgcn_s_setprio(0);
    __builtin_amdgcn_s_barrier();
    // ---- P3 ----
    if (t + 2 < nt) stageHalf(t + 2, 3);
    __builtin_amdgcn_s_barrier();
    __builtin_amdgcn_s_setprio(1);
#pragma unroll
    for (int i = 0; i < 4; i++)
#pragma unroll
      for (int j = 0; j < 2; j++)
#pragma unroll
        for (int s = 0; s < 2; s++)
          acc[i + 4][j + 2] = __builtin_amdgcn_mfma_f32_16x16x32_bf16(ahi[i][s], bj23[j][s], acc[i + 4][j + 2], 0, 0, 0);
    __builtin_amdgcn_s_setprio(0);
    __builtin_amdgcn_sched_barrier(0);
    if (t + 1 < nt) {
      if (t + 2 < nt) asm volatile("s_waitcnt vmcnt(4)" ::: "memory");
      else            asm volatile("s_waitcnt vmcnt(0)" ::: "memory");
      __builtin_amdgcn_sched_barrier(0);
    }
    __builtin_amdgcn_s_barrier();
  }

  if (EPI == 3) {
    // fold bias, store logits f32
    float bj[4];
#pragma unroll
    for (int j = 0; j < 4; j++) bj[j] = bias[n0 + wn * 64 + j * 16 + a];
#pragma unroll
    for (int i = 0; i < 8; i++)
#pragma unroll
      for (int j = 0; j < 4; j++)
#pragma unroll
        for (int r = 0; r < 4; r++) acc[i][j][r] += bj[j];
#pragma unroll
    for (int i = 0; i < 8; i++)
#pragma unroll
      for (int j = 0; j < 4; j++)
#pragma unroll
        for (int r = 0; r < 4; r++) {
          int mrow = m0 + wm * 128 + i * 16 + gg * 4 + r;
          int ncol = n0 + wn * 64 + j * 16 + a;
          outf[(size_t)mrow * ldo + ncol] = acc[i][j][r];
        }
    // two-pass per-row stats over this wave's 64-col strip (exact max, then sumexp)
    float2* sm = (float2*)lds;   // [256 rows][4 wn]
#pragma unroll
    for (int i = 0; i < 8; i++) {
#pragma unroll
      for (int r = 0; r < 4; r++) {
        float pm = fmaxf(fmaxf(acc[i][0][r], acc[i][1][r]),
                         fmaxf(acc[i][2][r], acc[i][3][r]));
#pragma unroll
        for (int off = 1; off < 16; off <<= 1) pm = fmaxf(pm, __shfl_xor(pm, off));
        float ps = __expf(acc[i][0][r] - pm) + __expf(acc[i][1][r] - pm) +
                   __expf(acc[i][2][r] - pm) + __expf(acc[i][3][r] - pm);
#pragma unroll
        for (int off = 1; off < 16; off <<= 1) ps += __shfl_xor(ps, off);
        if (a == 0) {
          float2 v2; v2.x = pm; v2.y = ps;
          sm[(wm * 128 + i * 16 + gg * 4 + r) * 4 + wn] = v2;
        }
      }
    }
    __syncthreads();
    if (tid < 256) {
      float2 p0 = sm[tid * 4 + 0], p1 = sm[tid * 4 + 1];
      float2 p2 = sm[tid * 4 + 2], p3 = sm[tid * 4 + 3];
      float M = fmaxf(fmaxf(p0.x, p1.x), fmaxf(p2.x, p3.x));
      float S = p0.y * __expf(p0.x - M) + p1.y * __expf(p1.x - M) +
                p2.y * __expf(p2.x - M) + p3.y * __expf(p3.x - M);
      float2 o2; o2.x = M; o2.y = S;
      part[(size_t)(m0 + tid) * 128 + (n0 >> 8)] = o2;
    }
    return;
  }

#pragma unroll
  for (int i = 0; i < 8; i++) {
#pragma unroll
    for (int j = 0; j < 4; j++) {
#pragma unroll
      for (int r = 0; r < 4; r++) {
        int mrow = m0 + wm * 128 + i * 16 + gg * 4 + r;
        int ncol = n0 + wn * 64 + j * 16 + a;
        float v = acc[i][j][r];
        if (EPI == 0) {
          int which = ncol >> 10;
          int n1 = ncol & 1023;
          int h = n1 >> 6, sidx = n1 & 63;
          int bb = mrow >> 10, tt = mrow & 1023;
          ushort* dst = (which == 0) ? outb : (which == 1) ? outk : outv;
          dst[(((size_t)(bb * N_HEAD + h)) * T_SEQ + tt) * HS + sidx] = f2bf(v);
        } else if (EPI == 2) {
          float t2 = v + bias[ncol];
          outb[(size_t)mrow * ldo + ncol] = f2bf(t2 > 0.0f ? t2 : 0.0f);
        }
      }
    }
  }
}

// ---------------- fused causal flash attention (LDS-staged K/V, R10-verified) ----------------
__global__ __launch_bounds__(256) void attn_kernel(const ushort* __restrict__ q,
                                                   const ushort* __restrict__ k,
                                                   const ushort* __restrict__ vT,
                                                   ushort* __restrict__ o) {
  __shared__ __align__(16) ushort Ksm[64 * 72];
  __shared__ __align__(16) ushort Vsm[64 * 72];
  __shared__ __align__(16) ushort Psm[4][16 * 72];
  int tid = threadIdx.x;
  int lane = tid & 63, w = tid >> 6;
  int a = lane & 15, gg = lane >> 4;
  int qt = blockIdx.x, bh = blockIdx.y;
  int qrow_b = qt * 64 + w * 16;
  int qmy = qrow_b + a;

  bf16x8 qf[2];
  const ushort* qbase = q + ((size_t)bh * T_SEQ + qmy) * HS;
  qf[0] = *(const bf16x8*)&qbase[gg * 8];
  qf[1] = *(const bf16x8*)&qbase[32 + gg * 8];

  float m_run = -__builtin_inff();
  float l_run = 0.0f;
  f32x4 oacc[4] = {};
  int nkt = qt + 1;

  for (int kt = 0; kt < nkt; kt++) {
    int k0 = kt * 64;
    __syncthreads();
#pragma unroll
    for (int i = 0; i < 2; i++) {
      int c = tid + i * 256;
      int row = c >> 3, cc = c & 7;
      *(int4*)&Ksm[row * 72 + cc * 8] =
          *(const int4*)&k[((size_t)bh * T_SEQ + k0 + row) * HS + cc * 8];
      *(int4*)&Vsm[row * 72 + cc * 8] =
          *(const int4*)&vT[((size_t)bh * HS + row) * T_SEQ + k0 + cc * 8];
    }
    __syncthreads();

    f32x4 st[4] = {};
#pragma unroll
    for (int ku = 0; ku < 4; ku++) {
#pragma unroll
      for (int s = 0; s < 2; s++) {
        bf16x8 kf = *(const bf16x8*)&Ksm[(ku * 16 + a) * 72 + s * 32 + gg * 8];
        st[ku] = __builtin_amdgcn_mfma_f32_16x16x32_bf16(kf, qf[s], st[ku], 0, 0, 0);
      }
    }

    float pv[16];
    float pm = -__builtin_inff();
#pragma unroll
    for (int ku = 0; ku < 4; ku++) {
#pragma unroll
      for (int r = 0; r < 4; r++) {
        int u = k0 + ku * 16 + gg * 4 + r;
        float val = (u <= qmy) ? st[ku][r] * ATTN_SCALE : -__builtin_inff();
        pv[ku * 4 + r] = val;
        pm = fmaxf(pm, val);
      }
    }
    pm = fmaxf(pm, __shfl_xor(pm, 16));
    pm = fmaxf(pm, __shfl_xor(pm, 32));
    float m_new = fmaxf(m_run, pm);
    float cfac = __expf(m_run - m_new);   // m_run=-inf first tile -> 0
    float tsum = 0.0f;
#pragma unroll
    for (int xi = 0; xi < 16; xi++) {
      float p = __expf(pv[xi] - m_new);
      pv[xi] = p;
      tsum += p;
    }
    tsum += __shfl_xor(tsum, 16);
    tsum += __shfl_xor(tsum, 32);
    l_run = l_run * cfac + tsum;
    m_run = m_new;

    ushort* P = (ushort*)&Psm[w][0];
    asm volatile("s_waitcnt lgkmcnt(0)" ::: "memory");
#pragma unroll
    for (int ku = 0; ku < 4; ku++) {
      ushort4 pw;
      pw.x = f2bf(pv[ku * 4 + 0]);
      pw.y = f2bf(pv[ku * 4 + 1]);
      pw.z = f2bf(pv[ku * 4 + 2]);
      pw.w = f2bf(pv[ku * 4 + 3]);
      *(ushort4*)&P[a * 72 + ku * 16 + gg * 4] = pw;
    }
#pragma unroll
    for (int r = 0; r < 4; r++) {
      float cr = __shfl(cfac, gg * 4 + r);
#pragma unroll
      for (int nb = 0; nb < 4; nb++) oacc[nb][r] *= cr;
    }
    asm volatile("s_waitcnt lgkmcnt(0)" ::: "memory");
#pragma unroll
    for (int kb = 0; kb < 2; kb++) {
      bf16x8 pa = *(const bf16x8*)&P[a * 72 + kb * 32 + gg * 8];
#pragma unroll
      for (int nb = 0; nb < 4; nb++) {
        bf16x8 vb = *(const bf16x8*)&Vsm[(nb * 16 + a) * 72 + kb * 32 + gg * 8];
        oacc[nb] = __builtin_amdgcn_mfma_f32_16x16x32_bf16(pa, vb, oacc[nb], 0, 0, 0);
      }
    }
  }

  float linv = 1.0f / l_run;
  int bb = bh >> 4, hh = bh & 15;
#pragma unroll
  for (int r = 0; r < 4; r++) {
    float li = __shfl(linv, gg * 4 + r);
    int qr = qrow_b + gg * 4 + r;
#pragma unroll
    for (int nb = 0; nb < 4; nb++) {
      o[((size_t)(bb * T_SEQ + qr)) * D_MODEL + hh * HS + nb * 16 + a] =
          f2bf(oacc[nb][r] * li);
    }
  }
}

// ---------------- loss: reduce per-block partials (125 per row) ----------------
__global__ __launch_bounds__(64) void loss_rows_kernel(const float2* __restrict__ part,
                                                       const float* __restrict__ logits,
                                                       const int* __restrict__ tgt,
                                                       float* __restrict__ row_loss) {
  int row = blockIdx.x;
  int l = threadIdx.x;
  float m = -__builtin_inff(), s = 0.0f;
#pragma unroll
  for (int q = 0; q < 2; q++) {
    int c = l * 2 + q;
    if (c < 125) {
      float2 p = part[(size_t)row * 128 + c];
      float nm = fmaxf(m, p.x);
      s = s * __expf(m - nm) + p.y * __expf(p.x - nm);
      m = nm;
    }
  }
#pragma unroll
  for (int off = 1; off < 64; off <<= 1) {
    float om = __shfl_xor(m, off), os = __shfl_xor(s, off);
    float nm = fmaxf(m, om);
    s = s * __expf(m - nm) + os * __expf(om - nm);
    m = nm;
  }
  if (l == 0)
    row_loss[row] = m + logf(s) - logits[(size_t)row * VOCAB + tgt[row]];
}

__global__ __launch_bounds__(256) void loss_final_kernel(const float* __restrict__ row_loss,
                                                         float* __restrict__ out) {
  int tid = threadIdx.x;
  __shared__ float red[4];
  float s = 0.0f;
  for (int i = tid; i < BT_ROWS; i += 256) s += row_loss[i];
  s = waveRedSum(s);
  if ((tid & 63) == 0) red[tid >> 6] = s;
  __syncthreads();
  if (tid == 0) out[0] = (red[0] + red[1] + red[2] + red[3]) * (1.0f / BT_ROWS);
}

// ---------------- orchestration ----------------
extern "C" void kernel_launch(void* const* d_in, const int* in_sizes, int n_in,
                              void* d_out, int out_size, void* d_ws, size_t ws_size,
                              hipStream_t stream) {
  const int* idx = (const int*)d_in[0];
  const int* tgt = (const int*)d_in[1];
  const float* tok_emb = (const float*)d_in[2];
  const float* pos_emb = (const float*)d_in[3];
  const float* Wq = (const float*)d_in[4];
  const float* Wk = (const float*)d_in[5];
  const float* Wv = (const float*)d_in[6];
  const float* proj_w = (const float*)d_in[7];
  const float* proj_b = (const float*)d_in[8];
  const float* ln1_g = (const float*)d_in[9];
  const float* ln1_b = (const float*)d_in[10];
  const float* ln2_g = (const float*)d_in[11];
  const float* ln2_b = (const float*)d_in[12];
  const float* ff_w1 = (const float*)d_in[13];
  const float* ff_b1 = (const float*)d_in[14];
  const float* ff_w2 = (const float*)d_in[15];
  const float* ff_b2 = (const float*)d_in[16];
  const float* lnf_g = (const float*)d_in[17];
  const float* lnf_b = (const float*)d_in[18];
  const float* head_w = (const float*)d_in[19];
  const float* head_b = (const float*)d_in[20];

  char* ws = (char*)d_ws;
  size_t off = 0;
  float* x = (float*)(ws + off); off += (size_t)BT_ROWS * D_MODEL * 4;
  ushort* h = (ushort*)(ws + off); off += (size_t)BT_ROWS * D_MODEL * 2;
  ushort* qb = (ushort*)(ws + off); off += (size_t)BT_ROWS * D_MODEL * 2;
  ushort* kb = (ushort*)(ws + off); off += (size_t)BT_ROWS * D_MODEL * 2;
  ushort* vb = (ushort*)(ws + off); off += (size_t)BT_ROWS * D_MODEL * 2;
  ushort* vTb = (ushort*)(ws + off); off += (size_t)BT_ROWS * D_MODEL * 2;
  ushort* ob = (ushort*)(ws + off); off += (size_t)BT_ROWS * D_MODEL * 2;
  ushort* ffb = (ushort*)(ws + off); off += (size_t)BT_ROWS * FF_DIM * 2;
  ushort* wqkvT = (ushort*)(ws + off); off += (size_t)4 * D_MODEL * D_MODEL * 2;
  ushort* wprojT = wqkvT + (size_t)3 * D_MODEL * D_MODEL;
  ushort* wff1T = (ushort*)(ws + off); off += (size_t)FF_DIM * D_MODEL * 2;
  ushort* wff2T = (ushort*)(ws + off); off += (size_t)D_MODEL * FF_DIM * 2;
  float* row_loss = (float*)(ws + off); off += (size_t)BT_ROWS * 4;
  float2* part = (float2*)(ws + off); off += (size_t)BT_ROWS * 128 * 8;   // 4 MB
  // head weights (32000x1024 bf16 = 65.5 MB) reuse the dead qb..ffb region (75.5 MB)
  ushort* headT = qb;

  float* logits = (float*)d_out;

  embed_kernel<<<BT_ROWS, 256, 0, stream>>>(idx, tok_emb, pos_emb, x);

  for (int l = 0; l < L_LAYERS; l++) {
    size_t wo = (size_t)l * D_MODEL * D_MODEL;
    size_t fo = (size_t)l * D_MODEL * FF_DIM;
    // all per-layer weight conversions in ONE launch
    wconv_layer_kernel<<<dim3(16, 16, 12), 256, 0, stream>>>(
        Wq + wo, Wk + wo, Wv + wo, proj_w + wo, ff_w1 + fo, ff_w2 + fo,
        wqkvT, wff1T, wff2T);

    ln_kernel<<<BT_ROWS / 4, 256, 0, stream>>>(x, ln1_g + l * D_MODEL, ln1_b + l * D_MODEL, h);
    // QKV gemm (N=3072): 256x256 fine-phase, grid 12x16
    gemm8_kernel<0, false><<<dim3(12, 16), 512, 131072, stream>>>(
        h, wqkvT, D_MODEL, nullptr, nullptr, qb, kb, vb, 0, nullptr);
    vtrans_kernel<<<dim3(16, 64), 256, 0, stream>>>(vb, vTb);
    attn_kernel<<<dim3(16, 64), 256, 0, stream>>>(qb, kb, vTb, ob);
    // proj + residual: 128x128 2-phase, grid 8x32
    gemmp_kernel<128, 128, 2, 2, 1><<<dim3(8, 32), 256, 0, stream>>>(
        ob, wprojT, D_MODEL, proj_b + l * D_MODEL, x, nullptr, nullptr, nullptr, D_MODEL);
    ln_kernel<<<BT_ROWS / 4, 256, 0, stream>>>(x, ln2_g + l * D_MODEL, ln2_b + l * D_MODEL, h);
    // FF1: 256x256 fine-phase, grid 16x16
    gemm8_kernel<2, false><<<dim3(16, 16), 512, 131072, stream>>>(
        h, wff1T, D_MODEL, ff_b1 + (size_t)l * FF_DIM, nullptr, ffb, nullptr, nullptr,
        FF_DIM, nullptr);
    // FF2 + residual: 128x128 2-phase, grid 8x32, K=4096
    gemmp_kernel<128, 128, 2, 2, 1><<<dim3(8, 32), 256, 0, stream>>>(
        ffb, wff2T, FF_DIM, ff_b2 + l * D_MODEL, x, nullptr, nullptr, nullptr, D_MODEL);
  }

  ln_kernel<<<BT_ROWS / 4, 256, 0, stream>>>(x, lnf_g, lnf_b, h);

  // head: one GEMM N=32000, fine-phase + ROW-MAJOR XCD swizzle + fused loss partials
  wconv_kernel<<<dim3(500, 16), 256, 0, stream>>>(head_w, headT, D_MODEL, VOCAB);
  gemm8_kernel<3, true><<<dim3(125, 16), 512, 131072, stream>>>(
      h, headT, D_MODEL, head_b, logits, nullptr, nullptr, nullptr, VOCAB, part);

  loss_rows_kernel<<<BT_ROWS, 64, 0, stream>>>(part, logits, tgt, row_loss);
  loss_final_kernel<<<1, 256, 0, stream>>>(row_loss, logits + (size_t)BT_ROWS * VOCAB);
}